// Round 2
// baseline (346.742 us; speedup 1.0000x reference)
//
#include <hip/hip_runtime.h>

// AssociativeScanGateLoop: h_t = f_t*h_{t-1} + i_t*v_t per (b,d) sequence.
// x: (B=4, T=8192, 3*512) fp32.  out: (4, 8192, 512) fp32.
// Two-kernel chunked scan, float4-vectorized (4 channels/thread, 16 B/lane).
// K1 computes per-chunk affine aggregates (A, KV); K2 folds predecessor
// aggregates into a starting state, recomputes the chunk, writes output.

#define B_   4
#define T_   8192
#define DH_  512
#define ROW4_ 384   // 1536 floats per (b,t) row = 384 float4
#define DG4_  128   // 512 floats per column = 128 float4

__device__ __forceinline__ float sigmoid_f(float x) {
    // 1/(1+e^-x); saturates to 0/1 gracefully when __expf overflows.
    return __fdividef(1.0f, 1.0f + __expf(-x));
}

__device__ __forceinline__ float tanh_f(float x) {
    // 1 - 2/(e^{2x}+1); saturates to +/-1 when __expf overflows.
    return 1.0f - __fdividef(2.0f, __expf(2.0f * x) + 1.0f);
}

// One scan step for a single lane-channel: update (A, KV) aggregate.
__device__ __forceinline__ void step_agg(float xv, float gv, float& A, float& K) {
    const float s  = sigmoid_f(gv);    // input gate
    const float f  = 1.0f - s;         // forget gate
    const float iv = tanh_f(xv) * s;
    A = f * A;
    K = f * K + iv;
}

// K1: per-chunk aggregate (A, KV) of the affine recurrence h' = A*h + KV.
// Reads columns 0 (input) and 1 (input gate) only: 128 MiB total.
__global__ __launch_bounds__(128) void k_partials(
        const float4* __restrict__ x4,
        float4* __restrict__ aggA,
        float4* __restrict__ aggKV,
        int C, int Tc) {
    const int c  = blockIdx.x;
    const int b  = blockIdx.y;
    const int d4 = threadIdx.x;            // 128 threads x 4 channels
    const float4* xb = x4 + (size_t)b * T_ * ROW4_;
    const int t0 = c * Tc;

    float4 A  = make_float4(1.0f, 1.0f, 1.0f, 1.0f);
    float4 KV = make_float4(0.0f, 0.0f, 0.0f, 0.0f);
#pragma unroll 4
    for (int i = 0; i < Tc; ++i) {
        const size_t r = (size_t)(t0 + i) * ROW4_ + d4;
        const float4 xi = xb[r];
        const float4 gi = xb[r + DG4_];
        step_agg(xi.x, gi.x, A.x, KV.x);
        step_agg(xi.y, gi.y, A.y, KV.y);
        step_agg(xi.z, gi.z, A.z, KV.z);
        step_agg(xi.w, gi.w, A.w, KV.w);
    }
    const size_t idx = ((size_t)b * C + c) * DG4_ + d4;
    aggA[idx]  = A;
    aggKV[idx] = KV;
}

// K2: fold predecessor aggregates (h_init = 0, so h0 = affine fold of KVs),
// then recompute the chunk with carried state and write gated output.
__global__ __launch_bounds__(128) void k_apply(
        const float4* __restrict__ x4,
        const float4* __restrict__ aggA,
        const float4* __restrict__ aggKV,
        float4* __restrict__ out4,
        int C, int Tc) {
    const int c  = blockIdx.x;
    const int b  = blockIdx.y;
    const int d4 = threadIdx.x;

    // Exclusive prefix over chunks [0, c). Aggregates are tiny (L2-hot).
    float4 h = make_float4(0.0f, 0.0f, 0.0f, 0.0f);
#pragma unroll 4
    for (int cc = 0; cc < c; ++cc) {
        const size_t idx = ((size_t)b * C + cc) * DG4_ + d4;
        const float4 a  = aggA[idx];
        const float4 kv = aggKV[idx];
        h.x = a.x * h.x + kv.x;
        h.y = a.y * h.y + kv.y;
        h.z = a.z * h.z + kv.z;
        h.w = a.w * h.w + kv.w;
    }

    const float4* xb = x4 + (size_t)b * T_ * ROW4_;
    float4* ob = out4 + (size_t)b * T_ * DG4_;
    const int t0 = c * Tc;

#pragma unroll 4
    for (int i = 0; i < Tc; ++i) {
        const size_t r = (size_t)(t0 + i) * ROW4_ + d4;
        const float4 xi = xb[r];
        const float4 gi = xb[r + DG4_];
        const float4 go = xb[r + 2 * DG4_];
        float4 o;
        {
            const float s = sigmoid_f(gi.x), f = 1.0f - s;
            h.x = f * h.x + tanh_f(xi.x) * s;
            o.x = tanh_f(h.x) * sigmoid_f(go.x);
        }
        {
            const float s = sigmoid_f(gi.y), f = 1.0f - s;
            h.y = f * h.y + tanh_f(xi.y) * s;
            o.y = tanh_f(h.y) * sigmoid_f(go.y);
        }
        {
            const float s = sigmoid_f(gi.z), f = 1.0f - s;
            h.z = f * h.z + tanh_f(xi.z) * s;
            o.z = tanh_f(h.z) * sigmoid_f(go.z);
        }
        {
            const float s = sigmoid_f(gi.w), f = 1.0f - s;
            h.w = f * h.w + tanh_f(xi.w) * s;
            o.w = tanh_f(h.w) * sigmoid_f(go.w);
        }
        ob[(size_t)(t0 + i) * DG4_ + d4] = o;
    }
}

extern "C" void kernel_launch(void* const* d_in, const int* in_sizes, int n_in,
                              void* d_out, int out_size, void* d_ws, size_t ws_size,
                              hipStream_t stream) {
    const float4* x4 = (const float4*)d_in[0];
    float4* out4 = (float4*)d_out;

    // C chunks (power of two dividing T); aggregates must fit in d_ws.
    int C = 256;
    while (C > 1 && (size_t)B_ * C * DH_ * 2 * sizeof(float) > ws_size) C >>= 1;
    const int Tc = T_ / C;

    float4* aggA  = (float4*)d_ws;
    float4* aggKV = aggA + (size_t)B_ * C * DG4_;

    dim3 grid(C, B_);
    dim3 block(128);
    hipLaunchKernelGGL(k_partials, grid, block, 0, stream, x4, aggA, aggKV, C, Tc);
    hipLaunchKernelGGL(k_apply,    grid, block, 0, stream, x4, aggA, aggKV, out4, C, Tc);
}